// Round 12
// baseline (210.846 us; speedup 1.0000x reference)
//
#include <hip/hip_runtime.h>
#include <math.h>

#define N_NODES 50000
#define E_EDGES 300000
#define E_TOT   350000   // E + N self-loops
#define NEG 0.2f
#define EPS 1e-16f
#define SCAN_BLOCKS 196  // 196*256 = 50176 >= 50000

typedef __attribute__((ext_vector_type(8))) short bf16x8;
typedef __attribute__((ext_vector_type(4))) float f32x4;

__device__ __forceinline__ float leaky(float x) { return x > 0.f ? x : NEG * x; }
// fp32 -> bf16 (RNE, finite inputs)
__device__ __forceinline__ short f2bf(float v) {
    unsigned u = __float_as_uint(v);
    u += 0x7fffu + ((u >> 16) & 1u);
    return (short)(u >> 16);
}
__device__ __forceinline__ float bflo(unsigned u) { return __uint_as_float(u << 16); }
__device__ __forceinline__ float bfhi(unsigned u) { return __uint_as_float(u & 0xffff0000u); }

// ---------------- CSR construction ----------------

__global__ __launch_bounds__(256) void k_hist(const int* __restrict__ ei,
        int* __restrict__ deg) {
    int e = blockIdx.x * 256 + threadIdx.x;
    if (e >= E_TOT) return;
    int d = (e < E_EDGES) ? ei[E_EDGES + e] : (e - E_EDGES);
    atomicAdd(&deg[d], 1);
}

__global__ __launch_bounds__(256) void k_blocksum(const int* __restrict__ deg,
        int* __restrict__ bsum) {
    int t = threadIdx.x;
    int idx = blockIdx.x * 256 + t;
    int v = (idx < N_NODES) ? deg[idx] : 0;
    #pragma unroll
    for (int off = 32; off > 0; off >>= 1) v += __shfl_down(v, off);
    __shared__ int ws[4];
    if ((t & 63) == 0) ws[t >> 6] = v;
    __syncthreads();
    if (t == 0) bsum[blockIdx.x] = ws[0] + ws[1] + ws[2] + ws[3];
}

__global__ __launch_bounds__(256) void k_scanb(const int* __restrict__ bsum,
        int* __restrict__ bofs) {
    __shared__ int sh[256];
    int t = threadIdx.x;
    sh[t] = (t < SCAN_BLOCKS) ? bsum[t] : 0;
    __syncthreads();
    for (int s = 1; s < 256; s <<= 1) {
        int v = (t >= s) ? sh[t - s] : 0;
        __syncthreads();
        sh[t] += v;
        __syncthreads();
    }
    bofs[t] = (t == 0) ? 0 : sh[t - 1];
}

__global__ __launch_bounds__(256) void k_rowptr(const int* __restrict__ deg,
        const int* __restrict__ bofs, int* __restrict__ rowptr,
        int* __restrict__ cursor) {
    __shared__ int sh[256];
    int t = threadIdx.x;
    int idx = blockIdx.x * 256 + t;
    int v = (idx < N_NODES) ? deg[idx] : 0;
    sh[t] = v;
    __syncthreads();
    for (int s = 1; s < 256; s <<= 1) {
        int u = (t >= s) ? sh[t - s] : 0;
        __syncthreads();
        sh[t] += u;
        __syncthreads();
    }
    int excl = sh[t] - v + bofs[blockIdx.x];
    if (idx < N_NODES) { rowptr[idx] = excl; cursor[idx] = excl; }
    if (idx == N_NODES) rowptr[N_NODES] = E_TOT;
}

__global__ __launch_bounds__(256) void k_scatter(const int* __restrict__ ei,
        int* __restrict__ cursor, int* __restrict__ eidx) {
    int e = blockIdx.x * 256 + threadIdx.x;
    if (e >= E_TOT) return;
    int s = (e < E_EDGES) ? ei[e] : (e - E_EDGES);
    int d = (e < E_EDGES) ? ei[E_EDGES + e] : (e - E_EDGES);
    int pos = atomicAdd(&cursor[d], 1);
    eidx[pos] = s;
}

// ---------------- prep: wsv = W1·a vectors, W1b (padded B^T), W2bT ----------

__global__ __launch_bounds__(256) void k_prep(const float* __restrict__ W1,
        const float* __restrict__ as1, const float* __restrict__ ad1,
        const float* __restrict__ W2, float* __restrict__ wsv,
        short* __restrict__ W1b, short* __restrict__ W2bT) {
    int t = blockIdx.x * 256 + threadIdx.x;      // grid 128 -> 32768 threads
    // W2bT[col][k] = W2[k][col]
    {
        int col = t >> 8, k = t & 255;
        W2bT[t] = f2bf(W2[k * 128 + col]);
    }
    // W1b[h][col][k] = W1[k][h*64+col], k padded 27->32
    if (t < 8192) {
        int h = t >> 11, col = (t >> 5) & 63, k = t & 31;
        W1b[t] = f2bf(k < 27 ? W1[k * 256 + h * 64 + col] : 0.f);
    }
    // wsv[k][j]: j<4 -> sum_d W1[k][j*64+d]*as1[j*64+d]; j>=4 -> ad1
    if (t < 216) {
        int k = t >> 3, j = t & 7;
        const float* av = (j < 4) ? (as1 + j * 64) : (ad1 + (j - 4) * 64);
        const float* wr = W1 + k * 256 + ((j & 3) * 64);
        float s = 0.f;
        for (int d = 0; d < 64; ++d) s += wr[d] * av[d];
        wsv[k * 8 + j] = s;
    }
}

// s1[n][0..3]=src half-scores, [4..7]=dst — direct from x via wsv (27->8 GEMV)
__global__ __launch_bounds__(256) void k_s1(const float* __restrict__ x,
        const float* __restrict__ wsv, float* __restrict__ s1) {
    int idx = blockIdx.x * 256 + threadIdx.x;    // grid 1563
    if (idx >= N_NODES * 8) return;
    int n = idx >> 3, j = idx & 7;
    float s = 0.f;
    #pragma unroll
    for (int k = 0; k < 27; ++k) s += x[n * 27 + k] * wsv[k * 8 + j];
    s1[idx] = s;
}

// ---------------- layer-1 aggregation in x-space (barrier-free) ----------------
// Half-wave per node (8 nodes/block, grid 6250). 4x-unrolled edge gather.
// Output xaggb[n][head][c] bf16 (c=0..31, zero-padded beyond 27).
__global__ __launch_bounds__(256) void k_aggx(const int* __restrict__ rowptr,
        const int* __restrict__ eidx, const float* __restrict__ x,
        const float* __restrict__ s1, short* __restrict__ xaggb) {
    int half = threadIdx.x >> 5;                 // 0..7
    int c = threadIdx.x & 31;
    int n = blockIdx.x * 8 + half;               // grid 6250 -> 50000 exact
    int beg = rowptr[n];
    int deg = rowptr[n + 1] - beg;               // uniform across half-wave
    float4 sdv = *(const float4*)(s1 + n * 8 + 4);
    float a0 = 0.f, a1 = 0.f, a2 = 0.f, a3 = 0.f;
    float z0 = 0.f, z1 = 0.f, z2 = 0.f, z3 = 0.f;
    bool cx = c < 27;
    int i = 0;
    for (; i + 4 <= deg; i += 4) {
        int s0 = eidx[beg + i + 0];
        int s1i = eidx[beg + i + 1];
        int s2i = eidx[beg + i + 2];
        int s3 = eidx[beg + i + 3];
        float4 sv0 = *(const float4*)(s1 + s0 * 8);
        float4 sv1 = *(const float4*)(s1 + s1i * 8);
        float4 sv2 = *(const float4*)(s1 + s2i * 8);
        float4 sv3 = *(const float4*)(s1 + s3 * 8);
        float xv0 = cx ? x[s0 * 27 + c] : 0.f;
        float xv1 = cx ? x[s1i * 27 + c] : 0.f;
        float xv2 = cx ? x[s2i * 27 + c] : 0.f;
        float xv3 = cx ? x[s3 * 27 + c] : 0.f;
        float e00 = __expf(leaky(sv0.x + sdv.x));
        float e01 = __expf(leaky(sv0.y + sdv.y));
        float e02 = __expf(leaky(sv0.z + sdv.z));
        float e03 = __expf(leaky(sv0.w + sdv.w));
        float e10 = __expf(leaky(sv1.x + sdv.x));
        float e11 = __expf(leaky(sv1.y + sdv.y));
        float e12 = __expf(leaky(sv1.z + sdv.z));
        float e13 = __expf(leaky(sv1.w + sdv.w));
        float e20 = __expf(leaky(sv2.x + sdv.x));
        float e21 = __expf(leaky(sv2.y + sdv.y));
        float e22 = __expf(leaky(sv2.z + sdv.z));
        float e23 = __expf(leaky(sv2.w + sdv.w));
        float e30 = __expf(leaky(sv3.x + sdv.x));
        float e31 = __expf(leaky(sv3.y + sdv.y));
        float e32 = __expf(leaky(sv3.z + sdv.z));
        float e33 = __expf(leaky(sv3.w + sdv.w));
        z0 += e00 + e10 + e20 + e30;
        z1 += e01 + e11 + e21 + e31;
        z2 += e02 + e12 + e22 + e32;
        z3 += e03 + e13 + e23 + e33;
        a0 += e00 * xv0 + e10 * xv1 + e20 * xv2 + e30 * xv3;
        a1 += e01 * xv0 + e11 * xv1 + e21 * xv2 + e31 * xv3;
        a2 += e02 * xv0 + e12 * xv1 + e22 * xv2 + e32 * xv3;
        a3 += e03 * xv0 + e13 * xv1 + e23 * xv2 + e33 * xv3;
    }
    for (; i < deg; ++i) {
        int s0 = eidx[beg + i];
        float4 sv = *(const float4*)(s1 + s0 * 8);
        float xv = cx ? x[s0 * 27 + c] : 0.f;
        float e0 = __expf(leaky(sv.x + sdv.x));
        float e1 = __expf(leaky(sv.y + sdv.y));
        float e2 = __expf(leaky(sv.z + sdv.z));
        float e3 = __expf(leaky(sv.w + sdv.w));
        z0 += e0; z1 += e1; z2 += e2; z3 += e3;
        a0 += e0 * xv; a1 += e1 * xv; a2 += e2 * xv; a3 += e3 * xv;
    }
    int base = n * 128 + c;
    xaggb[base]      = f2bf(a0 / (z0 + EPS));
    xaggb[base + 32] = f2bf(a1 / (z1 + EPS));
    xaggb[base + 64] = f2bf(a2 / (z2 + EPS));
    xaggb[base + 96] = f2bf(a3 / (z3 + EPS));
}

// ---------------- dense: expand (W1) + elu + GEMM2 + s2 (MFMA only) ---------
// Block = 16 nodes. Wave w = head w for expand; col-tiles {2w,2w+1} for GEMM2.
__global__ __launch_bounds__(256) void k_dense(const short* __restrict__ xaggb,
        const short* __restrict__ W1b, const short* __restrict__ W2bT,
        const float* __restrict__ b1, const float* __restrict__ as2,
        const float* __restrict__ ad2, short* __restrict__ h2b,
        float* __restrict__ s2) {
    __shared__ short O[16 * 264];                // out1' [m][col], padded stride
    __shared__ float P[4][2][16];                // s2 partials [wave][ps/pd][m]
    int w = threadIdx.x >> 6, l = threadIdx.x & 63;
    int n0 = blockIdx.x * 16;                    // grid 3125 -> 50000 exact
    int lane16 = l & 15, quad = l >> 4;
    f32x4 z4 = {0.f, 0.f, 0.f, 0.f};

    // Phase B: expand head w: [16x32] @ [32x64] -> elu -> O
    {
        bf16x8 a = *(const bf16x8*)(xaggb + (n0 + lane16) * 128 + w * 32 + quad * 8);
        f32x4 cacc[4];
        #pragma unroll
        for (int nt = 0; nt < 4; ++nt) {
            bf16x8 b = *(const bf16x8*)&W1b[w * 2048 + (nt * 16 + lane16) * 32 + quad * 8];
            cacc[nt] = __builtin_amdgcn_mfma_f32_16x16x32_bf16(a, b, z4, 0, 0, 0);
        }
        #pragma unroll
        for (int nt = 0; nt < 4; ++nt) {
            int col = w * 64 + nt * 16 + lane16;
            float bb = b1[col];
            #pragma unroll
            for (int r2 = 0; r2 < 4; ++r2) {
                float v = cacc[nt][r2] + bb;
                v = v > 0.f ? v : __expf(v) - 1.f;
                O[(quad * 4 + r2) * 264 + col] = f2bf(v);
            }
        }
    }
    __syncthreads();

    // Phase C: gemm2, wave w -> h2 col-tiles {2w, 2w+1}
    f32x4 acc2[2];
    acc2[0] = z4; acc2[1] = z4;
    for (int k0 = 0; k0 < 256; k0 += 32) {
        bf16x8 a2 = *(const bf16x8*)&O[lane16 * 264 + k0 + quad * 8];
        #pragma unroll
        for (int j = 0; j < 2; ++j) {
            int ct = 2 * w + j;
            bf16x8 b2 = *(const bf16x8*)&W2bT[(ct * 16 + lane16) * 256 + k0 + quad * 8];
            acc2[j] = __builtin_amdgcn_mfma_f32_16x16x32_bf16(a2, b2, acc2[j], 0, 0, 0);
        }
    }
    float ps[4] = {0.f, 0.f, 0.f, 0.f}, pd[4] = {0.f, 0.f, 0.f, 0.f};
    #pragma unroll
    for (int j = 0; j < 2; ++j) {
        int col = (2 * w + j) * 16 + lane16;
        float a_s = as2[col], a_d = ad2[col];
        #pragma unroll
        for (int r2 = 0; r2 < 4; ++r2) {
            ps[r2] += acc2[j][r2] * a_s;
            pd[r2] += acc2[j][r2] * a_d;
            h2b[(n0 + quad * 4 + r2) * 128 + col] = f2bf(acc2[j][r2]);
        }
    }
    #pragma unroll
    for (int off = 1; off <= 8; off <<= 1)
        #pragma unroll
        for (int r2 = 0; r2 < 4; ++r2) {
            ps[r2] += __shfl_xor(ps[r2], off);
            pd[r2] += __shfl_xor(pd[r2], off);
        }
    if (lane16 == 0) {
        #pragma unroll
        for (int r2 = 0; r2 < 4; ++r2) {
            P[w][0][quad * 4 + r2] = ps[r2];
            P[w][1][quad * 4 + r2] = pd[r2];
        }
    }
    __syncthreads();
    if (threadIdx.x < 32) {
        int m = threadIdx.x & 15, hd = threadIdx.x >> 4;
        s2[(n0 + m) * 4 + hd]     = P[2 * hd][0][m] + P[2 * hd + 1][0][m];
        s2[(n0 + m) * 4 + 2 + hd] = P[2 * hd][1][m] + P[2 * hd + 1][1][m];
    }
}

// -------- layer-2 aggregate: wave-per-node, no-max softmax, 4x unrolled ----

__global__ __launch_bounds__(256) void k_agg2_csr(const int* __restrict__ rowptr,
        const int* __restrict__ eidx, const float* __restrict__ s2,
        const short* __restrict__ h2b, const float* __restrict__ b2,
        const float* __restrict__ Wfc, const float* __restrict__ bfc,
        float* __restrict__ out) {
    int wave = threadIdx.x >> 6;
    int l = threadIdx.x & 63;
    int n = blockIdx.x * 4 + wave;           // grid 12500 -> exact
    int beg = rowptr[n];
    int deg = rowptr[n + 1] - beg;
    int h = l >> 5;
    float sd = s2[n * 4 + 2 + h];
    float2 acc = make_float2(0.f, 0.f);
    float z = 0.f;
    int i = 0;
    for (; i + 4 <= deg; i += 4) {
        int a0 = eidx[beg + i], a1 = eidx[beg + i + 1];
        int a2 = eidx[beg + i + 2], a3 = eidx[beg + i + 3];
        float e0 = __expf(leaky(s2[a0 * 4 + h] + sd));
        float e1 = __expf(leaky(s2[a1 * 4 + h] + sd));
        float e2 = __expf(leaky(s2[a2 * 4 + h] + sd));
        float e3 = __expf(leaky(s2[a3 * 4 + h] + sd));
        unsigned v0 = *(const unsigned*)(h2b + a0 * 128 + l * 2);
        unsigned v1 = *(const unsigned*)(h2b + a1 * 128 + l * 2);
        unsigned v2 = *(const unsigned*)(h2b + a2 * 128 + l * 2);
        unsigned v3 = *(const unsigned*)(h2b + a3 * 128 + l * 2);
        z += e0 + e1 + e2 + e3;
        acc.x += e0 * bflo(v0) + e1 * bflo(v1) + e2 * bflo(v2) + e3 * bflo(v3);
        acc.y += e0 * bfhi(v0) + e1 * bfhi(v1) + e2 * bfhi(v2) + e3 * bfhi(v3);
    }
    for (; i < deg; ++i) {
        int a0 = eidx[beg + i];
        float e0 = __expf(leaky(s2[a0 * 4 + h] + sd));
        unsigned v0 = *(const unsigned*)(h2b + a0 * 128 + l * 2);
        z += e0;
        acc.x += e0 * bflo(v0); acc.y += e0 * bfhi(v0);
    }
    float inv = 1.f / (z + EPS);
    float v0 = acc.x * inv + b2[l * 2];
    float v1 = acc.y * inv + b2[l * 2 + 1];
    v0 = v0 > 0.f ? v0 : __expf(v0) - 1.f;
    v1 = v1 > 0.f ? v1 : __expf(v1) - 1.f;
    float p = v0 * Wfc[l * 2] + v1 * Wfc[l * 2 + 1];
    #pragma unroll
    for (int off = 1; off <= 32; off <<= 1) p += __shfl_xor(p, off);
    if (l == 0) out[n] = 1.f / (1.f + __expf(-(p + bfc[0])));
}

extern "C" void kernel_launch(void* const* d_in, const int* in_sizes, int n_in,
                              void* d_out, int out_size, void* d_ws, size_t ws_size,
                              hipStream_t stream) {
    const float* x   = (const float*)d_in[0];
    const int*   ei  = (const int*)d_in[1];
    const float* W1  = (const float*)d_in[2];
    const float* as1 = (const float*)d_in[3];
    const float* ad1 = (const float*)d_in[4];
    const float* b1  = (const float*)d_in[5];
    const float* W2  = (const float*)d_in[6];
    const float* as2 = (const float*)d_in[7];
    const float* ad2 = (const float*)d_in[8];
    const float* b2  = (const float*)d_in[9];
    const float* Wfc = (const float*)d_in[10];
    const float* bfc = (const float*)d_in[11];
    float* out = (float*)d_out;

    float* f = (float*)d_ws;
    short* h2b   = (short*)f;                    // N*128 bf16
    short* xaggb = (short*)(f + 3200000);        // N*128 bf16 (4 heads x 32)
    float* s1    = f + 6400000;                  // N*8
    float* s2    = f + 6800000;                  // N*4
    float* wsv   = f + 7000000;                  // 27*8
    int*   rowptr= (int*)(f + 7010000);          // N+1
    int*   cursor= (int*)(f + 7070000);          // N
    int*   deg   = (int*)(f + 7130000);          // N
    int*   eidx  = (int*)(f + 7190000);          // E_TOT
    int*   bsum  = (int*)(f + 7540000);          // 256
    int*   bofs  = (int*)(f + 7541000);          // 256
    short* W1b   = (short*)(f + 7542000);        // 4*64*32 bf16
    short* W2bT  = (short*)(f + 7550000);        // 128*256 bf16

    // CSR build
    hipMemsetAsync(deg, 0, (size_t)N_NODES * 4, stream);
    k_hist<<<(E_TOT + 255) / 256, 256, 0, stream>>>(ei, deg);
    k_blocksum<<<SCAN_BLOCKS, 256, 0, stream>>>(deg, bsum);
    k_scanb<<<1, 256, 0, stream>>>(bsum, bofs);
    k_rowptr<<<SCAN_BLOCKS, 256, 0, stream>>>(deg, bofs, rowptr, cursor);
    k_scatter<<<(E_TOT + 255) / 256, 256, 0, stream>>>(ei, cursor, eidx);

    // weight prep + s1
    k_prep<<<128, 256, 0, stream>>>(W1, as1, ad1, W2, wsv, W1b, W2bT);
    k_s1<<<(N_NODES * 8 + 255) / 256, 256, 0, stream>>>(x, wsv, s1);

    // layer 1: x-space aggregation (latency-bound, barrier-free)
    k_aggx<<<6250, 256, 0, stream>>>(rowptr, eidx, x, s1, xaggb);

    // dense: expand + elu + GEMM2 -> h2b, s2 (MFMA-only)
    k_dense<<<3125, 256, 0, stream>>>(xaggb, W1b, W2bT, b1, as2, ad2, h2b, s2);

    // layer-2 aggregation + final FC + sigmoid
    k_agg2_csr<<<12500, 256, 0, stream>>>(rowptr, eidx, s2, h2b, b2, Wfc, bfc, out);
}